// Round 11
// baseline (10427.604 us; speedup 1.0000x reference)
//
#include <hip/hip_runtime.h>
#include <hip/hip_fp16.h>
#include <math.h>

#define BB 512
#define HH 256
#define SS 168
#define TT 24
#define NBLK 256
#define NTHR 256
typedef unsigned long long ull;
#define BH 131072ull  // 512*256

// ---- int area (from ws): per-group flags at ib + g*1024 ----
//   ife[0..168] tgt 32 | ifa 704+t tgt 32 | ifh0 736+t tgt 16 | ifh1 768+t tgt 16 | ifp 900 tgt 32
// ---- float offsets from fb = (float*)ws + 65536 ----
#define O_Y0  0ull        // y0 ring (2 slots used of 4)
#define O_H1  524288ull   // h1 ring, 2 slots
#define O_H0  786432ull   // dec h0 ring, 2 slots; slot1 doubles as zb during encoder
#define O_CTX 1048576ull  // 512 x 288 (cols 0..255 ctx, col 256 pred)
#define O_WT0 1196032ull  // enc l0 W^T [272][1024]
#define O_WT1 1474560ull  // enc l1 W^T [512][1024]
#define O_WD0 1998848ull  // dec c0 W^T [513][1024]
#define O_WD1 2524160ull  // dec c1 W^T [512][1024]
#define O_WDT 3048448ull  // Wd^T [256][256]
#define O_BP  3113984ull  // packed biases 4x1024 (e0,e1,d0,d1)
#define O_E16 3118080ull  // half[512][168][256]
#define O_P16 14128128ull // half[512][168][256]

typedef float v4f __attribute__((ext_vector_type(4)));

__device__ __forceinline__ float sigf(float x) { return 1.f / (1.f + expf(-x)); }

#define AR __ATOMIC_RELAXED
#define SCA __HIP_MEMORY_SCOPE_AGENT
__device__ __forceinline__ int aLd(int* p) { return __hip_atomic_load(p, AR, SCA); }
__device__ __forceinline__ int aAdd(int* p, int v) { return __hip_atomic_fetch_add(p, v, AR, SCA); }

// ---- UC transport: relaxed agent-scope (coherence-point) ops, no fences ----
__device__ __forceinline__ float2 ld2(const float* p) {
  ull raw = __hip_atomic_load((const ull*)p, AR, SCA);
  float2 v; v.x = __uint_as_float((unsigned)raw); v.y = __uint_as_float((unsigned)(raw >> 32));
  return v;
}
__device__ __forceinline__ float ld1(const float* p) {
  unsigned raw = __hip_atomic_load((const unsigned*)p, AR, SCA);
  return __uint_as_float(raw);
}
__device__ __forceinline__ void st1(float* p, float v) {
  __hip_atomic_store((unsigned*)p, __float_as_uint(v), AR, SCA);
}
__device__ __forceinline__ void sth(__half* p, __half v) {
  __hip_atomic_store((unsigned short*)p, __half_as_ushort(v), AR, SCA);
}
__device__ __forceinline__ void stu(unsigned* p, unsigned v) {
  __hip_atomic_store(p, v, AR, SCA);
}

// ---- manual-vmcnt loads (keep compiler vmem out of the pipelined loop) ----
// H: coalesced — lane (rr=tid>>3, j=tid&7) reads row rr, 16B at col j*4:
// 8 lanes cover one row's 128B contiguously (R7's 1KB-stride lanes fanned
// each wave-instr into ~64 txns; this is ~8).
__device__ __forceinline__ void ld_h4(const float* p, v4f& a) {
  asm volatile("global_load_dwordx4 %0, %1, off sc0 sc1"
               : "=&v"(a) : "v"(p) : "memory");
}
struct W4 { v4f v[4]; };
__device__ __forceinline__ void ld_w(const float* p, W4& w) {
  asm volatile("global_load_dwordx4 %0, %4, off\n\t"
               "global_load_dwordx4 %1, %5, off\n\t"
               "global_load_dwordx4 %2, %6, off\n\t"
               "global_load_dwordx4 %3, %7, off"
               : "=&v"(w.v[0]), "=&v"(w.v[1]), "=&v"(w.v[2]), "=&v"(w.v[3])
               : "v"(p), "v"(p + 1024), "v"(p + 2048), "v"(p + 3072) : "memory");
}
#define VMW(n) asm volatile("s_waitcnt vmcnt(" #n ")" ::: "memory")
// Raw barrier WITHOUT the compiler's vmcnt(0) drain (__syncthreads lowers to
// "s_waitcnt vmcnt(0) lgkmcnt(0); s_barrier" — that drain killed the R7
// prefetch every chunk). LDS hazards still fenced via lgkmcnt(0).
#define RAW_BAR() do { asm volatile("s_waitcnt lgkmcnt(0)" ::: "memory"); \
                       __builtin_amdgcn_s_barrier(); } while (0)

// ---- flag sync: no fences; data at coherence point before arrive ----
__device__ __forceinline__ void poll(int* f, int tgt) {
  while (aLd(f) < tgt) __builtin_amdgcn_s_sleep(1);
}
__device__ __forceinline__ void flag_arrive(int* f) {
  asm volatile("s_waitcnt vmcnt(0)" ::: "memory");
  __syncthreads();
  if (threadIdx.x == 0) aAdd(f, 1);
}
__device__ __forceinline__ void flag_wait2(int* f0, int t0, int* f1, int t1) {
  if (threadIdx.x == 0 && f0) poll(f0, t0);
  if (threadIdx.x == 64 && f1) poll(f1, t1);
  __syncthreads();
}

// ---- LDS (R7 layout, 21.5 KB — proven to launch) ----
struct SMT {
  union {
    struct { float Ws[32][132]; float Hs[32][36]; } a;   // 32r x 128gc tile
    struct { float As[32][65];  float Bs[32][65]; } g;   // enc_proj gemm
    struct { float h1s[256], qs[256], vs[256], sc[192], ctxs[512], sred[4]; } at;
  };
};

__device__ __forceinline__ void stage_W128h(const float* wTk, int gc0, float Ws[32][132]) { // 16 kk
  const int tid = threadIdx.x, gcq = tid & 31, kk2 = tid >> 5;
#pragma unroll
  for (int i = 0; i < 2; i++) {
    const int kk = kk2 * 2 + i;
    *(float4*)&Ws[kk][gcq * 4] = *(const float4*)(wTk + (ull)kk * 1024 + gc0 + gcq * 4);
  }
}

__device__ __forceinline__ void fma16(float acc[4][4], const float4 hv, const float4 wv) {
  acc[0][0] += hv.x * wv.x; acc[0][1] += hv.x * wv.y; acc[0][2] += hv.x * wv.z; acc[0][3] += hv.x * wv.w;
  acc[1][0] += hv.y * wv.x; acc[1][1] += hv.y * wv.y; acc[1][2] += hv.y * wv.z; acc[1][3] += hv.y * wv.w;
  acc[2][0] += hv.z * wv.x; acc[2][1] += hv.z * wv.y; acc[2][2] += hv.z * wv.z; acc[2][3] += hv.z * wv.w;
  acc[3][0] += hv.w * wv.x; acc[3][1] += hv.w * wv.y; acc[3][2] += hv.w * wv.z; acc[3][3] += hv.w * wv.w;
}
__device__ __forceinline__ void comp128(float Ws[32][132], float Hs[32][36], int bq, int ul,
                                        float acc[4][4], int nkk) {
#pragma unroll 8
  for (int kk = 0; kk < nkk; kk++)
    fma16(acc, *(const float4*)&Hs[kk][bq * 4], *(const float4*)&Ws[kk][ul * 4]);
}

// ---------------------------------------------------------------------------
// Software-pipelined gate-GEMM over NC 32-K chunks (R7 structure). W and H
// prefetched 1 chunk ahead; VMW(5) = the 5 newest loads (4 W + 1 H of chunk
// c+1) stay in flight while chunk c computes — and now SURVIVE the barrier
// (RAW_BAR has no vmcnt drain). Junk prefetch beyond NC stays inside ws;
// drained by the final VMW(0) before register reuse.
// ---------------------------------------------------------------------------
__device__ void gemm_pipe(const float* hb0, const float* hb1, const float* wb,
                          int NC, int nc0, float acc[4][4], SMT& sm)
{
  const int tid = threadIdx.x;
  const int rr = tid >> 3, j = tid & 7;       // H coords: 8 lanes per row
  const int gcq = tid & 31, kk4 = tid >> 5;   // W staging coords
  const int bq = tid & 7, ul = tid >> 3;      // compute coords
  v4f hA, hB;
  W4 wA, wB;
  const float* h1p = hb1 - (ull)nc0 * 32;
  ld_h4(hb0, hA);
  ld_w(wb, wA);
  for (int c = 0; c < NC; c += 2) {
    ld_w(wb + (ull)(c + 1) * 32768, wB);
    ld_h4((c + 1 < nc0 ? hb0 + (c + 1) * 32 : h1p + (c + 1) * 32), hB);
    VMW(5);
#pragma unroll
    for (int i = 0; i < 4; i++) *(v4f*)&sm.a.Ws[kk4 * 4 + i][gcq * 4] = wA.v[i];
#pragma unroll
    for (int i = 0; i < 4; i++) sm.a.Hs[j * 4 + i][rr] = hA[i];
    RAW_BAR();
    comp128(sm.a.Ws, sm.a.Hs, bq, ul, acc, 32);
    RAW_BAR();
    ld_w(wb + (ull)(c + 2) * 32768, wA);
    ld_h4((c + 2 < nc0 ? hb0 + (c + 2) * 32 : h1p + (c + 2) * 32), hA);
    VMW(5);
#pragma unroll
    for (int i = 0; i < 4; i++) *(v4f*)&sm.a.Ws[kk4 * 4 + i][gcq * 4] = wB.v[i];
#pragma unroll
    for (int i = 0; i < 4; i++) sm.a.Hs[j * 4 + i][rr] = hB[i];
    RAW_BAR();
    comp128(sm.a.Ws, sm.a.Hs, bq, ul, acc, 32);
    RAW_BAR();
  }
  asm volatile("s_waitcnt vmcnt(0)" ::: "memory");  // junk drained before reg reuse
}

__device__ __forceinline__ void lstm_epi(float acc[4][4], float cReg[4], int row0, int u,
                                         float* hout, __half* e16, int sstep)
{
  const int bq = threadIdx.x & 7;
#pragma unroll
  for (int bd = 0; bd < 4; bd++) {
    const int row = row0 + bq * 4 + bd;
    const float iv = sigf(acc[bd][0]), fv = sigf(acc[bd][1]);
    const float gv = tanhf(acc[bd][2]), ov = sigf(acc[bd][3]);
    const float cn = fv * cReg[bd] + iv * gv;
    cReg[bd] = cn;
    const float hn = ov * tanhf(cn);
    st1(hout + (ull)row * 256 + u, hn);
    if (e16) sth(e16 + ((ull)row * SS + sstep) * 256 + u, __float2half(hn));
  }
}

// ---- attention + fc for one batch row (UC transport) ----
__device__ void attn_fc(int row, int t, int slot, const float* h1r, const float* wdT,
                        const float* attn_b, const float* attn_v,
                        const __half* P16, const __half* E16,
                        const float* fc_w, const float* fc_b,
                        float* ctxb, float* out, SMT& sm)
{
  const int tid = threadIdx.x;
  __syncthreads();
  if (tid < 128) {
    float2 v = ld2(h1r + (ull)slot * BH + (ull)row * 256 + tid * 2);
    sm.at.h1s[tid * 2] = v.x; sm.at.h1s[tid * 2 + 1] = v.y;
  }
  __syncthreads();
  if (t >= 1 && tid < 64) {
    float a = 0.f;
#pragma unroll
    for (int jj = 0; jj < 4; jj++) a += sm.at.h1s[tid + 64 * jj] * fc_w[tid + 64 * jj];
#pragma unroll
    for (int m = 32; m >= 1; m >>= 1) a += __shfl_xor(a, m, 64);
    if (tid == 0) {
      const float p = a + fc_b[0];
      out[(ull)row * TT + (t - 1)] = p;
      st1(ctxb + (ull)row * 288 + 256, p);
    }
  }
  if (t >= TT) return;
  float qv = attn_b[tid];
  for (int k = 0; k < 256; k += 4) {
    qv += sm.at.h1s[k]     * wdT[(ull)(k)     * 256 + tid];
    qv += sm.at.h1s[k + 1] * wdT[(ull)(k + 1) * 256 + tid];
    qv += sm.at.h1s[k + 2] * wdT[(ull)(k + 2) * 256 + tid];
    qv += sm.at.h1s[k + 3] * wdT[(ull)(k + 3) * 256 + tid];
  }
  sm.at.qs[tid] = qv;
  sm.at.vs[tid] = attn_v[tid];
  __syncthreads();
  const int wv = tid >> 6, lane = tid & 63;
  for (int s = wv; s < SS; s += 4) {
    const __half2* Pr = (const __half2*)(P16 + ((ull)row * SS + s) * 256);
    float a = 0.f;
#pragma unroll
    for (int jj = 0; jj < 2; jj++) {
      const int i2 = lane + 64 * jj;
      const float2 pv = __half22float2(Pr[i2]);
      const int g0 = i2 * 2;
      a += sm.at.vs[g0] * tanhf(pv.x + sm.at.qs[g0]);
      a += sm.at.vs[g0 + 1] * tanhf(pv.y + sm.at.qs[g0 + 1]);
    }
#pragma unroll
    for (int m = 32; m >= 1; m >>= 1) a += __shfl_xor(a, m, 64);
    if (lane == 0) sm.at.sc[s] = a;
  }
  __syncthreads();
  if (tid < 64) {
    float m = -1e30f;
    for (int i = tid; i < SS; i += 64) m = fmaxf(m, sm.at.sc[i]);
#pragma unroll
    for (int mm = 32; mm >= 1; mm >>= 1) m = fmaxf(m, __shfl_xor(m, mm, 64));
    if (tid == 0) sm.at.sred[0] = m;
  }
  __syncthreads();
  const float smax = sm.at.sred[0];
  if (tid < SS) sm.at.sc[tid] = expf(sm.at.sc[tid] - smax);
  __syncthreads();
  if (tid < 64) {
    float ssum = 0.f;
    for (int i = tid; i < SS; i += 64) ssum += sm.at.sc[i];
#pragma unroll
    for (int mm = 32; mm >= 1; mm >>= 1) ssum += __shfl_xor(ssum, mm, 64);
    if (tid == 0) sm.at.sred[1] = ssum;
  }
  __syncthreads();
  const float rinv = 1.f / sm.at.sred[1];
  const int u2 = tid & 127, sh = tid >> 7;
  float cx = 0.f, cy = 0.f;
  for (int s = sh * 84; s < sh * 84 + 84; s++) {
    const float w = sm.at.sc[s] * rinv;
    const float2 ev = __half22float2(*(const __half2*)(E16 + ((ull)row * SS + s) * 256 + u2 * 2));
    cx += w * ev.x; cy += w * ev.y;
  }
  sm.at.ctxs[sh * 256 + u2 * 2] = cx;
  sm.at.ctxs[sh * 256 + u2 * 2 + 1] = cy;
  __syncthreads();
  st1(ctxb + (ull)row * 288 + tid, sm.at.ctxs[tid] + sm.at.ctxs[256 + tid]);
}

// ---- enc_proj 64x64 gemm tile: P16 = E16 @ We^T; P16 stored UC ----
__device__ void proj_tile(const __half* E16, const float* attn_w, __half* P16,
                          int m0, int n0, SMT& sm)
{
  const int tid = threadIdx.x;
  const int mq = tid & 15, nq = tid >> 4;
  const int li = tid & 63, kq = tid >> 6;
  float acc[4][4] = {{0.f}};
  for (int k0 = 0; k0 < 256; k0 += 32) {
    float4 raw = *(const float4*)(E16 + (ull)(m0 + li) * 256 + k0 + kq * 8);
    const __half* hp = (const __half*)&raw;
#pragma unroll
    for (int i = 0; i < 8; i++) sm.g.As[kq * 8 + i][li] = __half2float(hp[i]);
    const float* gb = attn_w + (ull)(n0 + li) * 512 + k0 + kq * 8;
    const float4 v0 = *(const float4*)gb, v1 = *(const float4*)(gb + 4);
    sm.g.Bs[kq * 8 + 0][li] = v0.x; sm.g.Bs[kq * 8 + 1][li] = v0.y;
    sm.g.Bs[kq * 8 + 2][li] = v0.z; sm.g.Bs[kq * 8 + 3][li] = v0.w;
    sm.g.Bs[kq * 8 + 4][li] = v1.x; sm.g.Bs[kq * 8 + 5][li] = v1.y;
    sm.g.Bs[kq * 8 + 6][li] = v1.z; sm.g.Bs[kq * 8 + 7][li] = v1.w;
    __syncthreads();
#pragma unroll 8
    for (int kk = 0; kk < 32; kk++) {
      const float4 a4 = *(const float4*)&sm.g.As[kk][mq * 4];
      const float4 b4 = *(const float4*)&sm.g.Bs[kk][nq * 4];
      fma16(acc, a4, b4);
    }
    __syncthreads();
  }
#pragma unroll
  for (int i = 0; i < 4; i++) {
    const int m = m0 + mq * 4 + i;
#pragma unroll
    for (int jj = 0; jj < 2; jj++) {
      __half2 h2; h2.x = __float2half(acc[i][jj * 2]); h2.y = __float2half(acc[i][jj * 2 + 1]);
      stu((unsigned*)(P16 + (ull)m * 256 + n0 + nq * 4) + jj, *(unsigned*)&h2);
    }
  }
}

// ---------------------------------------------------------------------------
__global__ __launch_bounds__(256, 1) void seq2seq_pipe(
    const float* __restrict__ src,
    const float* __restrict__ attn_w, const float* __restrict__ attn_b,
    const float* __restrict__ attn_v,
    const float* __restrict__ fc_w, const float* __restrict__ fc_b,
    float* __restrict__ out, int* __restrict__ ib)
{
  __shared__ SMT sm;
  const int blk = blockIdx.x;
  const int tid = threadIdx.x;
  float* fb = (float*)ib + 65536;
  float* y0r  = fb + O_Y0;
  float* h1r  = fb + O_H1;
  float* h0r  = fb + O_H0;
  float* zb   = h0r + BH;          // zeroed by init; first overwritten at dec t=1
  float* ctxb = fb + O_CTX;
  const float* wT0 = fb + O_WT0;
  const float* wT1 = fb + O_WT1;
  const float* wD0 = fb + O_WD0;
  const float* wD1 = fb + O_WD1;
  const float* wdT = fb + O_WDT;
  const float* bp  = fb + O_BP;
  __half* E16 = (__half*)(fb + O_E16);
  __half* P16 = (__half*)(fb + O_P16);
  const int g = blk >> 5, m = blk & 31;
  const int rowg = g * 64;
  int* gf = ib + g * 1024;
  int* ife = gf;             // [0..168]
  int* ifa = gf + 704; int* ifh0 = gf + 736; int* ifh1 = gf + 768; int* ifp = gf + 900;

  const int rr = tid >> 3, j = tid & 7;       // H-load coords
  const int kk4 = tid >> 5, gcq = tid & 31;   // W coords
  const int bq = tid & 7, ul = tid >> 3;      // compute coords

  // tile geometry (same for both roles): 32 rows x 128 gate-cols
  const int lm = (m < 16) ? m : (m - 16);
  const int row0 = rowg + (lm & 1) * 32;
  const int gc0 = (lm >> 1) * 128;
  const int u = gc0 / 4 + ul;

  float cReg[4] = {0.f, 0.f, 0.f, 0.f};

  // ======== encoder: wavefront, single flag per iter (target 32) ========
  for (int t = 0; t <= SS; t++) {
    flag_wait2(t ? ife + (t - 1) : nullptr, 32, nullptr, 0);
    if (m < 16) {
      if (t < SS) {
        float acc[4][4];
        const float4 bv = *(const float4*)(bp + gc0 + ul * 4);
#pragma unroll
        for (int bd = 0; bd < 4; bd++) { acc[bd][0] = bv.x; acc[bd][1] = bv.y; acc[bd][2] = bv.z; acc[bd][3] = bv.w; }
        {  // x segment (16 k), cached loads (outside pipe loop)
          const int r = tid & 31, f = tid >> 5;
          sm.a.Hs[f][r]     = src[((ull)(row0 + r) * SS + t) * 16 + f];
          sm.a.Hs[f + 8][r] = src[((ull)(row0 + r) * SS + t) * 16 + f + 8];
        }
        stage_W128h(wT0, gc0, sm.a.Ws);
        __syncthreads();
        comp128(sm.a.Ws, sm.a.Hs, bq, ul, acc, 16);
        __syncthreads();
        const float* ysrc = (t == 0) ? zb : (y0r + (ull)((t + 1) & 1) * BH);
        const float* hb0 = ysrc + (ull)(row0 + rr) * 256 + j * 4;
        const float* wb = wT0 + 16 * 1024 + kk4 * 4096 + gc0 + gcq * 4;
        gemm_pipe(hb0, hb0, wb, 8, 8, acc, sm);
        lstm_epi(acc, cReg, row0, u, y0r + (ull)(t & 1) * BH, nullptr, 0);
      }
    } else {
      if (t >= 1) {
        const int s = t - 1;
        float acc[4][4];
        const float4 bv = *(const float4*)(bp + 1024 + gc0 + ul * 4);
#pragma unroll
        for (int bd = 0; bd < 4; bd++) { acc[bd][0] = bv.x; acc[bd][1] = bv.y; acc[bd][2] = bv.z; acc[bd][3] = bv.w; }
        const float* ysrc = y0r + (ull)(s & 1) * BH;
        const float* hsrc = (s == 0) ? zb : (h1r + (ull)((s + 1) & 1) * BH);
        const float* hb0 = ysrc + (ull)(row0 + rr) * 256 + j * 4;
        const float* hb1 = hsrc + (ull)(row0 + rr) * 256 + j * 4;
        const float* wb = wT1 + kk4 * 4096 + gc0 + gcq * 4;
        gemm_pipe(hb0, hb1, wb, 16, 8, acc, sm);
        lstm_epi(acc, cReg, row0, u, h1r + (ull)(s & 1) * BH, E16, s);
      }
    }
    flag_arrive(ife + t);
  }

  // ======== enc_proj: group-local rows, 21 tiles per block ========
  if (tid == 0) poll(ife + SS, 32);
  __syncthreads();
  {
    const int em0 = rowg * SS;
    for (int tau = m; tau < 672; tau += 32)
      proj_tile(E16, attn_w, P16, em0 + (tau >> 2) * 64, (tau & 3) * 64, sm);
  }
  flag_arrive(ifp);

  // ======== decoder (cReg NOT reset: cell0/cell1 inherit enc-final c0e/c1e
  //          under the identical (row,u) partition) ========
  for (int t = 0; t <= TT; t++) {
    if (t == 0) flag_wait2(ifp, 32, nullptr, 0);
    else flag_wait2(ifh1 + (t - 1), 16, nullptr, 0);
    const int slot = (t + 1) & 1;
    attn_fc(rowg + 2 * m,     t, slot, h1r, wdT, attn_b, attn_v, P16, E16, fc_w, fc_b, ctxb, out, sm);
    attn_fc(rowg + 2 * m + 1, t, slot, h1r, wdT, attn_b, attn_v, P16, E16, fc_w, fc_b, ctxb, out, sm);
    if (t == TT) break;
    flag_arrive(ifa + t);
    if (m < 16) {
      // ---- dec cell0: x = [ctx(256) | h0prev(256) | pred(1)] ----
      flag_wait2(ifa + t, 32, t ? ifh0 + (t - 1) : nullptr, 16);
      float acc[4][4];
      const float4 bv = *(const float4*)(bp + 2048 + gc0 + ul * 4);
#pragma unroll
      for (int bd = 0; bd < 4; bd++) { acc[bd][0] = bv.x; acc[bd][1] = bv.y; acc[bd][2] = bv.z; acc[bd][3] = bv.w; }
      const float* h0src = (t == 0) ? (y0r + BH) : (h0r + (ull)((t + 1) & 1) * BH);
      const float* hb0 = ctxb + (ull)(row0 + rr) * 288 + j * 4;
      const float* hb1 = h0src + (ull)(row0 + rr) * 256 + j * 4;
      const float* wb = wD0 + kk4 * 4096 + gc0 + gcq * 4;
      gemm_pipe(hb0, hb1, wb, 16, 8, acc, sm);
      const float4 wp = *(const float4*)(wD0 + 512ull * 1024 + gc0 + ul * 4);
#pragma unroll
      for (int bd = 0; bd < 4; bd++) {
        const int row = row0 + bq * 4 + bd;
        const float p = ld1(ctxb + (ull)row * 288 + 256);
        acc[bd][0] += p * wp.x; acc[bd][1] += p * wp.y; acc[bd][2] += p * wp.z; acc[bd][3] += p * wp.w;
      }
      lstm_epi(acc, cReg, row0, u, h0r + (ull)(t & 1) * BH, nullptr, 0);
      flag_arrive(ifh0 + t);
    } else {
      // ---- dec cell1: x = [h0new(256) | h1prev(256)] ----
      flag_wait2(ifh0 + t, 16, t ? ifh1 + (t - 1) : nullptr, 16);
      float acc[4][4];
      const float4 bv = *(const float4*)(bp + 3072 + gc0 + ul * 4);
#pragma unroll
      for (int bd = 0; bd < 4; bd++) { acc[bd][0] = bv.x; acc[bd][1] = bv.y; acc[bd][2] = bv.z; acc[bd][3] = bv.w; }
      const float* hb0 = h0r + (ull)(t & 1) * BH + (ull)(row0 + rr) * 256 + j * 4;
      const float* hb1 = h1r + (ull)((t + 1) & 1) * BH + (ull)(row0 + rr) * 256 + j * 4;
      const float* wb = wD1 + kk4 * 4096 + gc0 + gcq * 4;
      gemm_pipe(hb0, hb1, wb, 16, 8, acc, sm);
      lstm_epi(acc, cReg, row0, u, h1r + (ull)(t & 1) * BH, nullptr, 0);
      flag_arrive(ifh1 + t);
    }
  }
}

// ---------------------------------------------------------------------------
// Init: zero flags + zb, pre-transpose weights (col = u*4+gate), pack biases,
// seed ctx pred col with dec_in0.
// ---------------------------------------------------------------------------
__global__ void init_all(
    const float* __restrict__ src,
    const float* __restrict__ ewih0, const float* __restrict__ ewhh0, const float* __restrict__ eb0,
    const float* __restrict__ ewih1, const float* __restrict__ ewhh1, const float* __restrict__ eb1,
    const float* __restrict__ dwih0, const float* __restrict__ dwhh0, const float* __restrict__ db0,
    const float* __restrict__ dwih1, const float* __restrict__ dwhh1, const float* __restrict__ db1,
    const float* __restrict__ attn_w, int* __restrict__ ib)
{
  const int gid = blockIdx.x * 256 + threadIdx.x;
  const int NG = 1024 * 256;
  float* fb = (float*)ib + 65536;
  for (int i = gid; i < 8192; i += NG) ib[i] = 0;
  for (int i = gid; i < (int)BH; i += NG) fb[O_H0 + BH + i] = 0.f;   // zb
  for (int i = gid; i < 272 * 1024; i += NG) {
    const int k = i >> 10, cg = i & 1023, jj = (cg & 3) * 256 + (cg >> 2);
    fb[O_WT0 + i] = (k < 16) ? ewih0[(ull)jj * 16 + k] : ewhh0[(ull)jj * 256 + k - 16];
  }
  for (int i = gid; i < 512 * 1024; i += NG) {
    const int k = i >> 10, cg = i & 1023, jj = (cg & 3) * 256 + (cg >> 2);
    fb[O_WT1 + i] = (k < 256) ? ewih1[(ull)jj * 256 + k] : ewhh1[(ull)jj * 256 + k - 256];
  }
  for (int i = gid; i < 513 * 1024; i += NG) {
    const int k = i >> 10, cg = i & 1023, jj = (cg & 3) * 256 + (cg >> 2);
    float v;
    if (k < 256) v = dwih0[(ull)jj * 257 + 1 + k];
    else if (k < 512) v = dwhh0[(ull)jj * 256 + k - 256];
    else v = dwih0[(ull)jj * 257];
    fb[O_WD0 + i] = v;
  }
  for (int i = gid; i < 512 * 1024; i += NG) {
    const int k = i >> 10, cg = i & 1023, jj = (cg & 3) * 256 + (cg >> 2);
    fb[O_WD1 + i] = (k < 256) ? dwih1[(ull)jj * 256 + k] : dwhh1[(ull)jj * 256 + k - 256];
  }
  for (int i = gid; i < 256 * 256; i += NG) {
    const int k = i >> 8, gg = i & 255;
    fb[O_WDT + i] = attn_w[(ull)gg * 512 + 256 + k];
  }
  for (int i = gid; i < 4096; i += NG) {
    const int set = i >> 10, cg = i & 1023, jj = (cg & 3) * 256 + (cg >> 2);
    const float* bsrc = (set == 0) ? eb0 : (set == 1) ? eb1 : (set == 2) ? db0 : db1;
    fb[O_BP + i] = bsrc[jj];
  }
  for (int i = gid; i < 512; i += NG)
    fb[O_CTX + (ull)i * 288 + 256] = src[((ull)i * SS + 167) * 16 + 15];
}

extern "C" void kernel_launch(void* const* d_in, const int* in_sizes, int n_in,
                              void* d_out, int out_size, void* d_ws, size_t ws_size,
                              hipStream_t stream)
{
  const float* src    = (const float*)d_in[0];
  const float* ewih0  = (const float*)d_in[1];
  const float* ewhh0  = (const float*)d_in[2];
  const float* eb0    = (const float*)d_in[3];
  const float* ewih1  = (const float*)d_in[4];
  const float* ewhh1  = (const float*)d_in[5];
  const float* eb1    = (const float*)d_in[6];
  const float* dwih0  = (const float*)d_in[7];
  const float* dwhh0  = (const float*)d_in[8];
  const float* db0    = (const float*)d_in[9];
  const float* dwih1  = (const float*)d_in[10];
  const float* dwhh1  = (const float*)d_in[11];
  const float* db1    = (const float*)d_in[12];
  const float* attn_w = (const float*)d_in[13];
  const float* attn_b = (const float*)d_in[14];
  const float* attn_v = (const float*)d_in[15];
  // d_in[16] pos_bias: post-tanh, uniform over s -> softmax-invariant, unused.
  const float* fc_w   = (const float*)d_in[17];
  const float* fc_b   = (const float*)d_in[18];
  float* out = (float*)d_out;
  int* ib    = (int*)d_ws;

  init_all<<<1024, 256, 0, stream>>>(src, ewih0, ewhh0, eb0, ewih1, ewhh1, eb1,
                                     dwih0, dwhh0, db0, dwih1, dwhh1, db1, attn_w, ib);

  void* args[] = {
    (void*)&src, (void*)&attn_w, (void*)&attn_b, (void*)&attn_v,
    (void*)&fc_w, (void*)&fc_b, (void*)&out, (void*)&ib,
  };
  hipLaunchCooperativeKernel((const void*)seq2seq_pipe, dim3(NBLK), dim3(NTHR),
                             args, 0, stream);
}